// Round 1
// baseline (479.426 us; speedup 1.0000x reference)
//
#include <hip/hip_runtime.h>
#include <math.h>

#define NT 8192
#define NO 8192
#define FIN 256
#define FOUT 64
#define SPLIT 4
#define JS (NO/SPLIT)   // 2048 j per split
#define ROWT 64         // rows per attention block
#define TJ 64           // j tile

// workspace layout (float offsets)
#define OFF_HO  ((size_t)0)                           // 8192*64
#define OFF_ST  (OFF_HO + (size_t)NO*FOUT)            // 8192
#define OFF_SO  (OFF_ST + (size_t)NT)                 // 8192
#define OFF_WT  (OFF_SO + (size_t)NO)                 // 256
#define OFF_WO  (OFF_WT + (size_t)FIN)                // 256
#define OFF_NUM (OFF_WO + (size_t)FIN)                // 4*8192*64
#define OFF_DEN (OFF_NUM + (size_t)SPLIT*NT*FOUT)     // 4*8192
// total = 2,671,104 floats = 10.7 MB of d_ws

// K1: fold wt = W_t @ a_t, wo = W_o @ a_o  (256-vectors)
__global__ void k_wvec(const float* __restrict__ Wt, const float* __restrict__ Wo,
                       const float* __restrict__ a, float* __restrict__ ws) {
  int k = threadIdx.x;  // 0..255
  float s1 = 0.f, s2 = 0.f;
#pragma unroll
  for (int fq = 0; fq < FOUT/4; ++fq) {
    float4 wt4 = *(const float4*)(Wt + (size_t)k*FOUT + fq*4);
    float4 wo4 = *(const float4*)(Wo + (size_t)k*FOUT + fq*4);
    float4 at4 = *(const float4*)(a + fq*4);
    float4 ao4 = *(const float4*)(a + FOUT + fq*4);
    s1 += wt4.x*at4.x + wt4.y*at4.y + wt4.z*at4.z + wt4.w*at4.w;
    s2 += wo4.x*ao4.x + wo4.y*ao4.y + wo4.z*ao4.z + wo4.w*ao4.w;
  }
  ws[OFF_WT + k] = s1;
  ws[OFF_WO + k] = s2;
}

// K2: s_t = t_input @ wt   (wave per row)
__global__ void k_st(const float* __restrict__ tin, float* __restrict__ ws) {
  int lane = threadIdx.x & 63;
  int wv   = threadIdx.x >> 6;
  int row  = blockIdx.x * 4 + wv;
  float4 v = ((const float4*)(tin + (size_t)row*FIN))[lane];
  float4 w = ((const float4*)(ws + OFF_WT))[lane];
  float p = v.x*w.x + v.y*w.y + v.z*w.z + v.w*w.w;
#pragma unroll
  for (int m = 32; m >= 1; m >>= 1) p += __shfl_xor(p, m, 64);
  if (lane == 0) ws[OFF_ST + row] = p;
}

// K3: h_o = o_input @ W_o, fused s_o = h_o @ a_o.
// lane = output feature f (64), each wave does 8 rows; o-row loads are
// wave-uniform (readfirstlane forces scalarization), W_o loads coalesced.
__global__ void k_ho(const float* __restrict__ oin, const float* __restrict__ Wo,
                     const float* __restrict__ a, float* __restrict__ ws) {
  int lane = threadIdx.x & 63;
  int wv = __builtin_amdgcn_readfirstlane(threadIdx.x >> 6);
  int r0 = blockIdx.x * 32 + wv * 8;
  const float* ob = oin + (size_t)r0 * FIN;
  float acc[8];
#pragma unroll
  for (int r = 0; r < 8; ++r) acc[r] = 0.f;
#pragma unroll 2
  for (int k = 0; k < FIN; k += 4) {
    float w0 = Wo[(size_t)(k+0)*FOUT + lane];
    float w1 = Wo[(size_t)(k+1)*FOUT + lane];
    float w2 = Wo[(size_t)(k+2)*FOUT + lane];
    float w3 = Wo[(size_t)(k+3)*FOUT + lane];
#pragma unroll
    for (int r = 0; r < 8; ++r) {
      float4 ov = *(const float4*)(ob + (size_t)r*FIN + k);
      acc[r] = fmaf(ov.x, w0, acc[r]);
      acc[r] = fmaf(ov.y, w1, acc[r]);
      acc[r] = fmaf(ov.z, w2, acc[r]);
      acc[r] = fmaf(ov.w, w3, acc[r]);
    }
  }
  float ao = a[FOUT + lane];
#pragma unroll
  for (int r = 0; r < 8; ++r) {
    ws[OFF_HO + (size_t)(r0 + r)*FOUT + lane] = acc[r];
    float p = acc[r] * ao;
#pragma unroll
    for (int m = 32; m >= 1; m >>= 1) p += __shfl_xor(p, m, 64);
    if (lane == 0) ws[OFF_SO + r0 + r] = p;
  }
}

// K5: fused masked-softmax attention (no max subtraction: scores <= ~11,
// exp sums <= ~2e8, safe in fp32). Partial (num, den) per j-split to ws.
// Block: 64 rows x 2048 j (split). Per 64x64 tile: stage w (exp) transposed
// + h_o tile in LDS; each wave consumes 16 j with an 8x8 register block.
__launch_bounds__(256, 2)
__global__ void k_attn(const int* __restrict__ adj, float* __restrict__ ws) {
  const float* st = ws + OFF_ST;
  const float* so = ws + OFF_SO;
  const float* ho = ws + OFF_HO;
  float* gnum = ws + OFF_NUM;
  float* gden = ws + OFF_DEN;

  __shared__ float sT[ROWT];
  __shared__ __align__(16) float sO[JS];
  __shared__ __align__(16) float wT[TJ][68];   // [j_local][i_local], pad 68
  __shared__ __align__(16) float hT[TJ][68];   // [j_local][f]
  __shared__ float denp[ROWT][16];

  int t  = threadIdx.x;
  int bx = blockIdx.x;
  int s  = bx & (SPLIT - 1);
  int bi = bx >> 2;
  int i0 = bi * ROWT;
  int jbase = s * JS;

  if (t < ROWT) sT[t] = st[i0 + t];
#pragma unroll
  for (int q = 0; q < JS/1024; ++q) {          // 512 float4 / 256 thr
    int u = q*256 + t;
    ((float4*)sO)[u] = ((const float4*)(so + jbase))[u];
  }
#pragma unroll
  for (int q = 0; q < 4; ++q) ((float*)denp)[q*256 + t] = 0.f;

  float acc[8][8];
#pragma unroll
  for (int r = 0; r < 8; ++r)
#pragma unroll
    for (int f = 0; f < 8; ++f) acc[r][f] = 0.f;

  int wv = t >> 6, lane = t & 63;
  int ig = lane >> 3, fg = lane & 7;

  for (int tt = 0; tt < JS/TJ; ++tt) {
    int j0 = jbase + tt*TJ;
    __syncthreads();
    // ---- stage: adj -> w (transposed), den partials ----
#pragma unroll
    for (int q = 0; q < 4; ++q) {
      int u = q*256 + t;
      int il = u >> 4, cs = u & 15;
      const int4 av = *(const int4*)(adj + (size_t)(i0 + il)*NO + j0 + cs*4);
      float sti = sT[il];
      int ob = tt*TJ + cs*4;
      float x0 = sti + sO[ob+0]; x0 = fmaxf(x0, 0.2f*x0);
      float x1 = sti + sO[ob+1]; x1 = fmaxf(x1, 0.2f*x1);
      float x2 = sti + sO[ob+2]; x2 = fmaxf(x2, 0.2f*x2);
      float x3 = sti + sO[ob+3]; x3 = fmaxf(x3, 0.2f*x3);
      float w0 = (av.x > 0) ? __expf(x0) : 0.f;
      float w1 = (av.y > 0) ? __expf(x1) : 0.f;
      float w2 = (av.z > 0) ? __expf(x2) : 0.f;
      float w3 = (av.w > 0) ? __expf(x3) : 0.f;
      wT[cs*4+0][il] = w0;
      wT[cs*4+1][il] = w1;
      wT[cs*4+2][il] = w2;
      wT[cs*4+3][il] = w3;
      denp[il][cs] += w0 + w1 + w2 + w3;       // unique (il,cs) owner per thread
    }
    // ---- stage: h_o tile ----
#pragma unroll
    for (int q = 0; q < 4; ++q) {
      int u = q*256 + t;
      int jl = u >> 4, fs = u & 15;
      *(float4*)&hT[jl][fs*4] = *(const float4*)(ho + (size_t)(j0 + jl)*FOUT + fs*4);
    }
    __syncthreads();
    // ---- consume: wave wv takes j in [wv*16, wv*16+16) ----
#pragma unroll 4
    for (int jj = 0; jj < 16; ++jj) {
      int jl = wv*16 + jj;
      float4 wa = *(const float4*)&wT[jl][ig*8];
      float4 wb = *(const float4*)&wT[jl][ig*8 + 4];
      float4 ha = *(const float4*)&hT[jl][fg*8];
      float4 hb = *(const float4*)&hT[jl][fg*8 + 4];
      float wr[8] = {wa.x, wa.y, wa.z, wa.w, wb.x, wb.y, wb.z, wb.w};
      float hr[8] = {ha.x, ha.y, ha.z, ha.w, hb.x, hb.y, hb.z, hb.w};
#pragma unroll
      for (int r = 0; r < 8; ++r)
#pragma unroll
        for (int f = 0; f < 8; ++f)
          acc[r][f] = fmaf(wr[r], hr[f], acc[r][f]);
    }
  }
  __syncthreads();
  // ---- merge the 4 waves' j-partials (reuse wT as [il][f] buffer) ----
  for (int w = 0; w < 4; ++w) {
    if (wv == w) {
#pragma unroll
      for (int r = 0; r < 8; ++r) {
        float* p = &wT[ig*8 + r][fg*8];
        if (w == 0) {
#pragma unroll
          for (int f = 0; f < 8; ++f) p[f] = acc[r][f];
        } else {
#pragma unroll
          for (int f = 0; f < 8; ++f) p[f] += acc[r][f];
        }
      }
    }
    __syncthreads();
  }
  // ---- write num/den partials ----
#pragma unroll
  for (int q = 0; q < 4; ++q) {
    int u = q*256 + t;
    int il = u >> 4, fs = u & 15;
    *(float4*)(gnum + ((size_t)s*NT + i0 + il)*FOUT + fs*4) = *(const float4*)&wT[il][fs*4];
  }
  if (t < ROWT) {
    float d = 0.f;
#pragma unroll
    for (int cs = 0; cs < 16; ++cs) d += denp[t][cs];
    gden[(size_t)s*NT + i0 + t] = d;
  }
}

// K6: combine splits, normalize, ELU
__global__ void k_comb(const float* __restrict__ ws, float* __restrict__ out) {
  int idx = blockIdx.x * 256 + threadIdx.x;   // 0..524287
  int i = idx >> 6;
  float num = 0.f, den = 0.f;
#pragma unroll
  for (int s = 0; s < SPLIT; ++s) {
    num += ws[OFF_NUM + ((size_t)s*NT + i)*FOUT + (idx & 63)];
    den += ws[OFF_DEN + (size_t)s*NT + i];
  }
  float r = num / den;
  out[idx] = (r > 0.f) ? r : (__expf(r) - 1.f);
}

extern "C" void kernel_launch(void* const* d_in, const int* in_sizes, int n_in,
                              void* d_out, int out_size, void* d_ws, size_t ws_size,
                              hipStream_t stream) {
  const float* tin = (const float*)d_in[0];
  const float* oin = (const float*)d_in[1];
  const float* Wt  = (const float*)d_in[2];
  const float* Wo  = (const float*)d_in[3];
  const float* a   = (const float*)d_in[4];
  const int*   adj = (const int*)d_in[5];
  float* out = (float*)d_out;
  float* ws  = (float*)d_ws;

  hipLaunchKernelGGL(k_wvec, dim3(1),            dim3(256), 0, stream, Wt, Wo, a, ws);
  hipLaunchKernelGGL(k_st,   dim3(NT/4),         dim3(256), 0, stream, tin, ws);
  hipLaunchKernelGGL(k_ho,   dim3(NO/32),        dim3(256), 0, stream, oin, Wo, a, ws);
  hipLaunchKernelGGL(k_attn, dim3(NT/ROWT*SPLIT), dim3(256), 0, stream, adj, ws);
  hipLaunchKernelGGL(k_comb, dim3(NT*FOUT/256),  dim3(256), 0, stream, ws, out);
}

// Round 2
// 473.684 us; speedup vs baseline: 1.0121x; 1.0121x over previous
//
#include <hip/hip_runtime.h>
#include <math.h>

#define NT 8192
#define NO 8192
#define FIN 256
#define FOUT 64
#define SPLIT 4
#define JS (NO/SPLIT)   // 2048 j per split
#define ROWT 64         // rows per attention block
#define TJ 64           // j tile

// workspace layout (float offsets)
#define OFF_ST  ((size_t)0)                           // 8192
#define OFF_SO  (OFF_ST + (size_t)NT)                 // 8192
#define OFF_WT  (OFF_SO + (size_t)NO)                 // 256
#define OFF_WO  (OFF_WT + (size_t)FIN)                // 256
#define OFF_NUM (OFF_WO + (size_t)FIN)                // 4*8192*64
#define OFF_DEN (OFF_NUM + (size_t)SPLIT*NT*FOUT)     // 4*8192
#define OFF_HOB (OFF_DEN + (size_t)SPLIT*NT)          // 8192*64 bf16 = 262144 floats
// total = 2,408,960 floats = 9.64 MB of d_ws

typedef __attribute__((ext_vector_type(8))) short short8;
typedef __attribute__((ext_vector_type(4))) float float4v;

static __device__ __forceinline__ unsigned short f2bf(float x) {
  unsigned int u = __float_as_uint(x);
  unsigned int r = (u + 0x7fffu + ((u >> 16) & 1u)) >> 16;   // RNE
  return (unsigned short)r;
}
static __device__ __forceinline__ float bf2f(unsigned short b) {
  return __uint_as_float(((unsigned int)b) << 16);
}

// K1: fold wt = W_t @ a_t, wo = W_o @ a_o  (256-vectors)
__global__ void k_wvec(const float* __restrict__ Wt, const float* __restrict__ Wo,
                       const float* __restrict__ a, float* __restrict__ ws) {
  int k = threadIdx.x;  // 0..255
  float s1 = 0.f, s2 = 0.f;
#pragma unroll
  for (int fq = 0; fq < FOUT/4; ++fq) {
    float4 wt4 = *(const float4*)(Wt + (size_t)k*FOUT + fq*4);
    float4 wo4 = *(const float4*)(Wo + (size_t)k*FOUT + fq*4);
    float4 at4 = *(const float4*)(a + fq*4);
    float4 ao4 = *(const float4*)(a + FOUT + fq*4);
    s1 += wt4.x*at4.x + wt4.y*at4.y + wt4.z*at4.z + wt4.w*at4.w;
    s2 += wo4.x*ao4.x + wo4.y*ao4.y + wo4.z*ao4.z + wo4.w*ao4.w;
  }
  ws[OFF_WT + k] = s1;
  ws[OFF_WO + k] = s2;
}

// K2: s_t = t_input @ wt   (wave per row)
__global__ void k_st(const float* __restrict__ tin, float* __restrict__ ws) {
  int lane = threadIdx.x & 63;
  int wv   = threadIdx.x >> 6;
  int row  = blockIdx.x * 4 + wv;
  float4 v = ((const float4*)(tin + (size_t)row*FIN))[lane];
  float4 w = ((const float4*)(ws + OFF_WT))[lane];
  float p = v.x*w.x + v.y*w.y + v.z*w.z + v.w*w.w;
#pragma unroll
  for (int m = 32; m >= 1; m >>= 1) p += __shfl_xor(p, m, 64);
  if (lane == 0) ws[OFF_ST + row] = p;
}

// K3: h_o = o_input @ W_o (fp32), outputs: hoT bf16 [f][j] (for MFMA B-frags)
// and s_o = h_o @ a_o (fp32).
__global__ void k_ho(const float* __restrict__ oin, const float* __restrict__ Wo,
                     const float* __restrict__ a, float* __restrict__ ws) {
  unsigned short* hob = (unsigned short*)(ws + OFF_HOB);
  int lane = threadIdx.x & 63;
  int wv = __builtin_amdgcn_readfirstlane(threadIdx.x >> 6);
  int r0 = blockIdx.x * 32 + wv * 8;
  const float* ob = oin + (size_t)r0 * FIN;
  float acc[8];
#pragma unroll
  for (int r = 0; r < 8; ++r) acc[r] = 0.f;
#pragma unroll 2
  for (int k = 0; k < FIN; k += 4) {
    float w0 = Wo[(size_t)(k+0)*FOUT + lane];
    float w1 = Wo[(size_t)(k+1)*FOUT + lane];
    float w2 = Wo[(size_t)(k+2)*FOUT + lane];
    float w3 = Wo[(size_t)(k+3)*FOUT + lane];
#pragma unroll
    for (int r = 0; r < 8; ++r) {
      float4 ov = *(const float4*)(ob + (size_t)r*FIN + k);
      acc[r] = fmaf(ov.x, w0, acc[r]);
      acc[r] = fmaf(ov.y, w1, acc[r]);
      acc[r] = fmaf(ov.z, w2, acc[r]);
      acc[r] = fmaf(ov.w, w3, acc[r]);
    }
  }
  float ao = a[FOUT + lane];
#pragma unroll
  for (int r = 0; r < 8; ++r) {
    hob[(size_t)lane*NO + r0 + r] = f2bf(acc[r]);   // transposed bf16 store
    float p = acc[r] * ao;
#pragma unroll
    for (int m = 32; m >= 1; m >>= 1) p += __shfl_xor(p, m, 64);
    if (lane == 0) ws[OFF_SO + r0 + r] = p;
  }
}

// K5: fused masked-softmax attention with MFMA P·V.
// No max subtraction needed: scores <= ~11, exp sums <= ~2e8 (fp32-safe).
// Block: 64 rows x JS j-split. Per 64x64 tile: stage w=exp(leaky(s_t+s_o))*mask
// as bf16 row-major [i][j] + h_o tile bf16 [f][j]; 4 waves each compute one
// 32x32 output quadrant via mfma_f32_16x16x32_bf16 (2x2 frags, K=64).
__launch_bounds__(256, 2)
__global__ void k_attn(const int* __restrict__ adj, float* __restrict__ ws) {
  const float* st = ws + OFF_ST;
  const float* so = ws + OFF_SO;
  const unsigned short* hob = (const unsigned short*)(ws + OFF_HOB);
  float* gnum = ws + OFF_NUM;
  float* gden = ws + OFF_DEN;

  __shared__ float sT[ROWT];
  __shared__ __align__(16) float sO[JS];
  __shared__ __align__(16) unsigned short wB[TJ][72];   // [i][j], stride 144B
  __shared__ __align__(16) unsigned short hB[TJ][72];   // [f][j], stride 144B
  __shared__ float denp[ROWT][16];

  int t  = threadIdx.x;
  int bx = blockIdx.x;
  int s  = bx & (SPLIT - 1);
  int bi = bx >> 2;
  int i0 = bi * ROWT;
  int jbase = s * JS;

  if (t < ROWT) sT[t] = st[i0 + t];
#pragma unroll
  for (int q = 0; q < JS/1024; ++q) {          // 512 float4 / 256 thr
    int u = q*256 + t;
    ((float4*)sO)[u] = ((const float4*)(so + jbase))[u];
  }
#pragma unroll
  for (int q = 0; q < 4; ++q) ((float*)denp)[q*256 + t] = 0.f;

  int wv = t >> 6, lane = t & 63;
  int iq = (wv >> 1) * 32;        // wave's output quadrant
  int fq = (wv & 1) * 32;
  int lm = lane & 15;             // MFMA m/n index
  int lk = (lane >> 4) * 8;       // MFMA k base (bf16 elements)

  float4v acc[2][2];
#pragma unroll
  for (int mi = 0; mi < 2; ++mi)
#pragma unroll
    for (int fi = 0; fi < 2; ++fi) acc[mi][fi] = (float4v)0.f;

  int hf = t >> 2;                // h-stage: feature row
  int hj = (t & 3) * 16;          // h-stage: j offset

  for (int tt = 0; tt < JS/TJ; ++tt) {
    int j0 = jbase + tt*TJ;
    __syncthreads();
    // ---- stage: adj -> w bf16 row-major, den partials (from rounded w) ----
#pragma unroll
    for (int q = 0; q < 4; ++q) {
      int u = q*256 + t;
      int il = u >> 4, cs = u & 15;
      const int4 av = *(const int4*)(adj + (size_t)(i0 + il)*NO + j0 + cs*4);
      float sti = sT[il];
      int ob = tt*TJ + cs*4;
      float x0 = sti + sO[ob+0]; x0 = fmaxf(x0, 0.2f*x0);
      float x1 = sti + sO[ob+1]; x1 = fmaxf(x1, 0.2f*x1);
      float x2 = sti + sO[ob+2]; x2 = fmaxf(x2, 0.2f*x2);
      float x3 = sti + sO[ob+3]; x3 = fmaxf(x3, 0.2f*x3);
      float w0 = (av.x > 0) ? __expf(x0) : 0.f;
      float w1 = (av.y > 0) ? __expf(x1) : 0.f;
      float w2 = (av.z > 0) ? __expf(x2) : 0.f;
      float w3 = (av.w > 0) ? __expf(x3) : 0.f;
      ushort4 wp;
      wp.x = f2bf(w0); wp.y = f2bf(w1); wp.z = f2bf(w2); wp.w = f2bf(w3);
      *(ushort4*)&wB[il][cs*4] = wp;
      // den from the *rounded* weights so num/den stay consistent
      denp[il][cs] += bf2f(wp.x) + bf2f(wp.y) + bf2f(wp.z) + bf2f(wp.w);
    }
    // ---- stage: h_o tile bf16 [f][j] ----
    {
      const unsigned short* hg = hob + (size_t)hf*NO + j0 + hj;
      int4 h0 = *(const int4*)(hg);
      int4 h1 = *(const int4*)(hg + 8);
      *(int4*)&hB[hf][hj]     = h0;
      *(int4*)&hB[hf][hj + 8] = h1;
    }
    __syncthreads();
    // ---- MFMA consume: 2x2 frags of 16x16x32, K=64 per tile ----
#pragma unroll
    for (int kk = 0; kk < 2; ++kk) {
      short8 a0 = *(const short8*)&wB[iq      + lm][kk*32 + lk];
      short8 a1 = *(const short8*)&wB[iq + 16 + lm][kk*32 + lk];
      short8 b0 = *(const short8*)&hB[fq      + lm][kk*32 + lk];
      short8 b1 = *(const short8*)&hB[fq + 16 + lm][kk*32 + lk];
      acc[0][0] = __builtin_amdgcn_mfma_f32_16x16x32_bf16(a0, b0, acc[0][0], 0, 0, 0);
      acc[0][1] = __builtin_amdgcn_mfma_f32_16x16x32_bf16(a0, b1, acc[0][1], 0, 0, 0);
      acc[1][0] = __builtin_amdgcn_mfma_f32_16x16x32_bf16(a1, b0, acc[1][0], 0, 0, 0);
      acc[1][1] = __builtin_amdgcn_mfma_f32_16x16x32_bf16(a1, b1, acc[1][1], 0, 0, 0);
    }
  }
  __syncthreads();
  // ---- write num partials (each wave owns its quadrant; coalesced) ----
#pragma unroll
  for (int mi = 0; mi < 2; ++mi)
#pragma unroll
    for (int fi = 0; fi < 2; ++fi)
#pragma unroll
      for (int r = 0; r < 4; ++r) {
        int i = i0 + iq + mi*16 + (lane >> 4)*4 + r;   // C/D: row=(lane>>4)*4+reg
        int f = fq + fi*16 + lm;                        //      col=lane&15
        gnum[((size_t)s*NT + i)*FOUT + f] = acc[mi][fi][r];
      }
  if (t < ROWT) {
    float d = 0.f;
#pragma unroll
    for (int cs = 0; cs < 16; ++cs) d += denp[t][cs];
    gden[(size_t)s*NT + i0 + t] = d;
  }
}

// K6: combine splits, normalize, ELU
__global__ void k_comb(const float* __restrict__ ws, float* __restrict__ out) {
  int idx = blockIdx.x * 256 + threadIdx.x;   // 0..524287
  int i = idx >> 6;
  float num = 0.f, den = 0.f;
#pragma unroll
  for (int s = 0; s < SPLIT; ++s) {
    num += ws[OFF_NUM + ((size_t)s*NT + i)*FOUT + (idx & 63)];
    den += ws[OFF_DEN + (size_t)s*NT + i];
  }
  float r = num / den;
  out[idx] = (r > 0.f) ? r : (__expf(r) - 1.f);
}

extern "C" void kernel_launch(void* const* d_in, const int* in_sizes, int n_in,
                              void* d_out, int out_size, void* d_ws, size_t ws_size,
                              hipStream_t stream) {
  const float* tin = (const float*)d_in[0];
  const float* oin = (const float*)d_in[1];
  const float* Wt  = (const float*)d_in[2];
  const float* Wo  = (const float*)d_in[3];
  const float* a   = (const float*)d_in[4];
  const int*   adj = (const int*)d_in[5];
  float* out = (float*)d_out;
  float* ws  = (float*)d_ws;

  hipLaunchKernelGGL(k_wvec, dim3(1),             dim3(256), 0, stream, Wt, Wo, a, ws);
  hipLaunchKernelGGL(k_st,   dim3(NT/4),          dim3(256), 0, stream, tin, ws);
  hipLaunchKernelGGL(k_ho,   dim3(NO/32),         dim3(256), 0, stream, oin, Wo, a, ws);
  hipLaunchKernelGGL(k_attn, dim3(NT/ROWT*SPLIT), dim3(256), 0, stream, adj, ws);
  hipLaunchKernelGGL(k_comb, dim3(NT*FOUT/256),   dim3(256), 0, stream, ws, out);
}

// Round 3
// 471.895 us; speedup vs baseline: 1.0160x; 1.0038x over previous
//
#include <hip/hip_runtime.h>
#include <math.h>

#define NT 8192
#define NO 8192
#define FIN 256
#define FOUT 64
#define SPLIT 8
#define JSP (NO/SPLIT)  // 1024 j per split
#define ROWT 64         // rows per attention block (4 waves x 16 rows)

// workspace layout (float offsets)
#define OFF_ST  ((size_t)0)                           // 8192
#define OFF_SO  (OFF_ST + (size_t)NT)                 // 8192
#define OFF_WT  (OFF_SO + (size_t)NO)                 // 256
#define OFF_WO  (OFF_WT + (size_t)FIN)                // 256
#define OFF_NUM (OFF_WO + (size_t)FIN)                // SPLIT*8192*64
#define OFF_DEN (OFF_NUM + (size_t)SPLIT*NT*FOUT)     // SPLIT*8192
#define OFF_HOB (OFF_DEN + (size_t)SPLIT*NT)          // 8192*64 bf16 = 262144 floats
// total ~= 4.7M floats ~= 19 MB of d_ws

typedef __attribute__((ext_vector_type(8))) short short8;
typedef __attribute__((ext_vector_type(4))) float float4v;

static __device__ __forceinline__ unsigned short f2bf(float x) {
  unsigned int u = __float_as_uint(x);
  unsigned int r = (u + 0x7fffu + ((u >> 16) & 1u)) >> 16;   // RNE
  return (unsigned short)r;
}
static __device__ __forceinline__ float bf2f(unsigned short b) {
  return __uint_as_float(((unsigned int)b) << 16);
}

// K1: fold wt = W_t @ a_t, wo = W_o @ a_o  (256-vectors)
__global__ void k_wvec(const float* __restrict__ Wt, const float* __restrict__ Wo,
                       const float* __restrict__ a, float* __restrict__ ws) {
  int k = threadIdx.x;  // 0..255
  float s1 = 0.f, s2 = 0.f;
#pragma unroll
  for (int fq = 0; fq < FOUT/4; ++fq) {
    float4 wt4 = *(const float4*)(Wt + (size_t)k*FOUT + fq*4);
    float4 wo4 = *(const float4*)(Wo + (size_t)k*FOUT + fq*4);
    float4 at4 = *(const float4*)(a + fq*4);
    float4 ao4 = *(const float4*)(a + FOUT + fq*4);
    s1 += wt4.x*at4.x + wt4.y*at4.y + wt4.z*at4.z + wt4.w*at4.w;
    s2 += wo4.x*ao4.x + wo4.y*ao4.y + wo4.z*ao4.z + wo4.w*ao4.w;
  }
  ws[OFF_WT + k] = s1;
  ws[OFF_WO + k] = s2;
}

// K2: s_t = t_input @ wt   (wave per row)
__global__ void k_st(const float* __restrict__ tin, float* __restrict__ ws) {
  int lane = threadIdx.x & 63;
  int wv   = threadIdx.x >> 6;
  int row  = blockIdx.x * 4 + wv;
  float4 v = ((const float4*)(tin + (size_t)row*FIN))[lane];
  float4 w = ((const float4*)(ws + OFF_WT))[lane];
  float p = v.x*w.x + v.y*w.y + v.z*w.z + v.w*w.w;
#pragma unroll
  for (int m = 32; m >= 1; m >>= 1) p += __shfl_xor(p, m, 64);
  if (lane == 0) ws[OFF_ST + row] = p;
}

// K3: h_o = o_input @ W_o (fp32), outputs: hob bf16 [f][j] (MFMA B source)
// and s_o = h_o @ a_o (fp32).
__global__ void k_ho(const float* __restrict__ oin, const float* __restrict__ Wo,
                     const float* __restrict__ a, float* __restrict__ ws) {
  unsigned short* hob = (unsigned short*)(ws + OFF_HOB);
  int lane = threadIdx.x & 63;
  int wv = __builtin_amdgcn_readfirstlane(threadIdx.x >> 6);
  int r0 = blockIdx.x * 32 + wv * 8;
  const float* ob = oin + (size_t)r0 * FIN;
  float acc[8];
#pragma unroll
  for (int r = 0; r < 8; ++r) acc[r] = 0.f;
#pragma unroll 2
  for (int k = 0; k < FIN; k += 4) {
    float w0 = Wo[(size_t)(k+0)*FOUT + lane];
    float w1 = Wo[(size_t)(k+1)*FOUT + lane];
    float w2 = Wo[(size_t)(k+2)*FOUT + lane];
    float w3 = Wo[(size_t)(k+3)*FOUT + lane];
#pragma unroll
    for (int r = 0; r < 8; ++r) {
      float4 ov = *(const float4*)(ob + (size_t)r*FIN + k);
      acc[r] = fmaf(ov.x, w0, acc[r]);
      acc[r] = fmaf(ov.y, w1, acc[r]);
      acc[r] = fmaf(ov.z, w2, acc[r]);
      acc[r] = fmaf(ov.w, w3, acc[r]);
    }
  }
  float ao = a[FOUT + lane];
#pragma unroll
  for (int r = 0; r < 8; ++r) {
    hob[(size_t)lane*NO + r0 + r] = f2bf(acc[r]);   // transposed bf16 store
    float p = acc[r] * ao;
#pragma unroll
    for (int m = 32; m >= 1; m >>= 1) p += __shfl_xor(p, m, 64);
    if (lane == 0) ws[OFF_SO + r0 + r] = p;
  }
}

// K5: fused masked-softmax attention. ZERO LDS, ZERO barriers.
// Each wave autonomously owns 16 rows x JSP j. Per 32-j tile:
//   lane builds the MFMA A-fragment IN REGISTERS:
//     A[m=lane&15][k=(lane>>4)*8+e] = w(i0+wv*16+m, j0+(lane>>4)*8+e)
//   where w = adj ? exp(leaky(s_t+s_o)) : 0, bf16-rounded.
//   B-frags read directly from global hob[f][j] (1 MB, L2-resident).
//   4 MFMAs (f-groups) accumulate the 16x64 output; den accumulates in-lane
//   from the SAME rounded w, reduced via shfl butterfly at the end.
// 2-stage register pipeline keeps next tile's loads in flight over the MFMAs.
__launch_bounds__(256, 4)
__global__ void k_attn(const int* __restrict__ adj, float* __restrict__ ws) {
  const float* st = ws + OFF_ST;
  const float* so = ws + OFF_SO;
  const unsigned short* hob = (const unsigned short*)(ws + OFF_HOB);
  float* gnum = ws + OFF_NUM;
  float* gden = ws + OFF_DEN;

  int t = threadIdx.x;
  int wv = t >> 6, lane = t & 63;
  int bx = blockIdx.x;
  int s  = bx & (SPLIT - 1);
  int bi = bx >> 3;                 // log2(SPLIT)
  int i0 = bi * ROWT;
  int jb = s * JSP;

  int r16 = lane & 15;              // MFMA m (row) / B n (feature-in-group)
  int kg  = lane >> 4;              // k-group 0..3
  int irow = i0 + wv*16 + r16;

  float sti = st[irow];

  const int* ap            = adj + (size_t)irow*NO + jb + kg*8;
  const float* sop         = so + jb + kg*8;
  const unsigned short* hp = hob + (size_t)r16*NO + jb + kg*8;

  float4v acc[4];
#pragma unroll
  for (int g = 0; g < 4; ++g) acc[g] = (float4v)0.f;
  float dsum = 0.f;

  int4   A0[2], A1[2];
  float4 S0[2], S1[2];
  short8 B[2][4];

  auto load = [&](int buf, int tt) {
    const int* a = ap + tt*32;
    A0[buf] = *(const int4*)a;
    A1[buf] = *(const int4*)(a + 4);
    const float* sp = sop + tt*32;
    S0[buf] = *(const float4*)sp;
    S1[buf] = *(const float4*)(sp + 4);
#pragma unroll
    for (int g = 0; g < 4; ++g)
      B[buf][g] = *(const short8*)(hp + (size_t)g*16*NO + tt*32);
  };

  auto compute = [&](int buf) {
    int   m[8] = {A0[buf].x, A0[buf].y, A0[buf].z, A0[buf].w,
                  A1[buf].x, A1[buf].y, A1[buf].z, A1[buf].w};
    float v[8] = {S0[buf].x, S0[buf].y, S0[buf].z, S0[buf].w,
                  S1[buf].x, S1[buf].y, S1[buf].z, S1[buf].w};
    short8 afrag;
#pragma unroll
    for (int e = 0; e < 8; ++e) {
      float x = sti + v[e];
      x = fmaxf(x, 0.2f * x);                 // leaky relu
      float w = (m[e] > 0) ? __expf(x) : 0.f;
      unsigned short us = f2bf(w);
      afrag[e] = (short)us;
      dsum += bf2f(us);                       // den from the ROUNDED weight
    }
#pragma unroll
    for (int g = 0; g < 4; ++g)
      acc[g] = __builtin_amdgcn_mfma_f32_16x16x32_bf16(afrag, B[buf][g], acc[g], 0, 0, 0);
  };

  load(0, 0);
#pragma unroll 2
  for (int tt = 0; tt < JSP/32 - 1; ++tt) {
    load((tt + 1) & 1, tt + 1);
    compute(tt & 1);
  }
  compute((JSP/32 - 1) & 1);

  // den: sum the 4 k-group partials per row
  dsum += __shfl_xor(dsum, 16, 64);
  dsum += __shfl_xor(dsum, 32, 64);
  if (lane < 16) gden[(size_t)s*NT + i0 + wv*16 + lane] = dsum;

  // num partials: C/D layout col=lane&15, row=(lane>>4)*4+reg
#pragma unroll
  for (int g = 0; g < 4; ++g)
#pragma unroll
    for (int r = 0; r < 4; ++r) {
      int i = i0 + wv*16 + kg*4 + r;
      int f = g*16 + r16;
      gnum[((size_t)s*NT + i)*FOUT + f] = acc[g][r];
    }
}

// K6: combine splits, normalize, ELU
__global__ void k_comb(const float* __restrict__ ws, float* __restrict__ out) {
  int idx = blockIdx.x * 256 + threadIdx.x;   // 0..524287
  int i = idx >> 6;
  float num = 0.f, den = 0.f;
#pragma unroll
  for (int s = 0; s < SPLIT; ++s) {
    num += ws[OFF_NUM + ((size_t)s*NT + i)*FOUT + (idx & 63)];
    den += ws[OFF_DEN + (size_t)s*NT + i];
  }
  float r = num / den;
  out[idx] = (r > 0.f) ? r : (__expf(r) - 1.f);
}

extern "C" void kernel_launch(void* const* d_in, const int* in_sizes, int n_in,
                              void* d_out, int out_size, void* d_ws, size_t ws_size,
                              hipStream_t stream) {
  const float* tin = (const float*)d_in[0];
  const float* oin = (const float*)d_in[1];
  const float* Wt  = (const float*)d_in[2];
  const float* Wo  = (const float*)d_in[3];
  const float* a   = (const float*)d_in[4];
  const int*   adj = (const int*)d_in[5];
  float* out = (float*)d_out;
  float* ws  = (float*)d_ws;

  hipLaunchKernelGGL(k_wvec, dim3(1),              dim3(256), 0, stream, Wt, Wo, a, ws);
  hipLaunchKernelGGL(k_st,   dim3(NT/4),           dim3(256), 0, stream, tin, ws);
  hipLaunchKernelGGL(k_ho,   dim3(NO/32),          dim3(256), 0, stream, oin, Wo, a, ws);
  hipLaunchKernelGGL(k_attn, dim3(NT/ROWT*SPLIT),  dim3(256), 0, stream, adj, ws);
  hipLaunchKernelGGL(k_comb, dim3(NT*FOUT/256),    dim3(256), 0, stream, ws, out);
}

// Round 4
// 463.265 us; speedup vs baseline: 1.0349x; 1.0186x over previous
//
#include <hip/hip_runtime.h>
#include <math.h>

#define NT 8192
#define NO 8192
#define FIN 256
#define FOUT 64
#define SPLIT 8
#define JSP (NO/SPLIT)  // 1024 j per split
#define ROWT 64         // rows per attention block (4 waves x 16 rows)

// workspace layout (float offsets)
#define OFF_ST  ((size_t)0)                           // 8192
#define OFF_SO  (OFF_ST + (size_t)NT)                 // 8192
#define OFF_WT  (OFF_SO + (size_t)NO)                 // 256
#define OFF_WO  (OFF_WT + (size_t)FIN)                // 256
#define OFF_NUM (OFF_WO + (size_t)FIN)                // SPLIT*8192*64
#define OFF_DEN (OFF_NUM + (size_t)SPLIT*NT*FOUT)     // SPLIT*8192
#define OFF_HOB (OFF_DEN + (size_t)SPLIT*NT)          // 8192*64 bf16
// total ~= 4.7M floats ~= 19 MB of d_ws

typedef __attribute__((ext_vector_type(8))) short short8;
typedef __attribute__((ext_vector_type(4))) float float4v;

static __device__ __forceinline__ unsigned short f2bf(float x) {
  unsigned int u = __float_as_uint(x);
  unsigned int r = (u + 0x7fffu + ((u >> 16) & 1u)) >> 16;   // RNE
  return (unsigned short)r;
}
// pack two fp32 -> two bf16 (RNE) in one int (elem0 low, elem1 high)
static __device__ __forceinline__ int pk2(float a, float b) {
  return (int)((unsigned int)f2bf(a) | ((unsigned int)f2bf(b) << 16));
}
static __device__ __forceinline__ float bflo(int p) {
  return __uint_as_float(((unsigned int)p) << 16);
}
static __device__ __forceinline__ float bfhi(int p) {
  return __uint_as_float(((unsigned int)p) & 0xffff0000u);
}

// K1: fold wt = W_t @ a_t, wo = W_o @ a_o  (256-vectors)
__global__ void k_wvec(const float* __restrict__ Wt, const float* __restrict__ Wo,
                       const float* __restrict__ a, float* __restrict__ ws) {
  int k = threadIdx.x;  // 0..255
  float s1 = 0.f, s2 = 0.f;
#pragma unroll
  for (int fq = 0; fq < FOUT/4; ++fq) {
    float4 wt4 = *(const float4*)(Wt + (size_t)k*FOUT + fq*4);
    float4 wo4 = *(const float4*)(Wo + (size_t)k*FOUT + fq*4);
    float4 at4 = *(const float4*)(a + fq*4);
    float4 ao4 = *(const float4*)(a + FOUT + fq*4);
    s1 += wt4.x*at4.x + wt4.y*at4.y + wt4.z*at4.z + wt4.w*at4.w;
    s2 += wo4.x*ao4.x + wo4.y*ao4.y + wo4.z*ao4.z + wo4.w*ao4.w;
  }
  ws[OFF_WT + k] = s1;
  ws[OFF_WO + k] = s2;
}

// K2: s_t = t_input @ wt   (wave per row)
__global__ void k_st(const float* __restrict__ tin, float* __restrict__ ws) {
  int lane = threadIdx.x & 63;
  int wv   = threadIdx.x >> 6;
  int row  = blockIdx.x * 4 + wv;
  float4 v = ((const float4*)(tin + (size_t)row*FIN))[lane];
  float4 w = ((const float4*)(ws + OFF_WT))[lane];
  float p = v.x*w.x + v.y*w.y + v.z*w.z + v.w*w.w;
#pragma unroll
  for (int m = 32; m >= 1; m >>= 1) p += __shfl_xor(p, m, 64);
  if (lane == 0) ws[OFF_ST + row] = p;
}

// K3: h_o = o_input @ W_o (fp32), outputs: hob bf16 [f][j] (MFMA B source)
// and s_o = h_o @ a_o (fp32).
__global__ void k_ho(const float* __restrict__ oin, const float* __restrict__ Wo,
                     const float* __restrict__ a, float* __restrict__ ws) {
  unsigned short* hob = (unsigned short*)(ws + OFF_HOB);
  int lane = threadIdx.x & 63;
  int wv = __builtin_amdgcn_readfirstlane(threadIdx.x >> 6);
  int r0 = blockIdx.x * 32 + wv * 8;
  const float* ob = oin + (size_t)r0 * FIN;
  float acc[8];
#pragma unroll
  for (int r = 0; r < 8; ++r) acc[r] = 0.f;
#pragma unroll 2
  for (int k = 0; k < FIN; k += 4) {
    float w0 = Wo[(size_t)(k+0)*FOUT + lane];
    float w1 = Wo[(size_t)(k+1)*FOUT + lane];
    float w2 = Wo[(size_t)(k+2)*FOUT + lane];
    float w3 = Wo[(size_t)(k+3)*FOUT + lane];
#pragma unroll
    for (int r = 0; r < 8; ++r) {
      float4 ov = *(const float4*)(ob + (size_t)r*FIN + k);
      acc[r] = fmaf(ov.x, w0, acc[r]);
      acc[r] = fmaf(ov.y, w1, acc[r]);
      acc[r] = fmaf(ov.z, w2, acc[r]);
      acc[r] = fmaf(ov.w, w3, acc[r]);
    }
  }
  float ao = a[FOUT + lane];
#pragma unroll
  for (int r = 0; r < 8; ++r) {
    hob[(size_t)lane*NO + r0 + r] = f2bf(acc[r]);   // transposed bf16 store
    float p = acc[r] * ao;
#pragma unroll
    for (int m = 32; m >= 1; m >>= 1) p += __shfl_xor(p, m, 64);
    if (lane == 0) ws[OFF_SO + r0 + r] = p;
  }
}

// K5: fused masked-softmax attention. Zero LDS, zero barriers, SINGLE-buffered,
// straight-line loop — register budget ~80 VGPR by construction (no spills
// under the 128-VGPR cap of launch_bounds(256,4)).
// A-fragment built in registers: A[m=lane&15][k=(lane>>4)*8+e] =
//   w(i0+wv*16+m, j0+(lane>>4)*8+e), w = adj ? exp(leaky(s_t+s_o)) : 0 (bf16).
// B-frags straight from global hob[f][j] (1 MB, L2-resident).
// 16 waves/CU of pure TLP saturate the adj HBM stream (268 MB -> ~42 us floor).
__launch_bounds__(256, 4)
__global__ void k_attn(const int* __restrict__ adj, float* __restrict__ ws) {
  const float* st = ws + OFF_ST;
  const float* so = ws + OFF_SO;
  const unsigned short* hob = (const unsigned short*)(ws + OFF_HOB);
  float* gnum = ws + OFF_NUM;
  float* gden = ws + OFF_DEN;

  int t = threadIdx.x;
  int wv = t >> 6, lane = t & 63;
  int bx = blockIdx.x;
  int s  = bx & (SPLIT - 1);
  int bi = bx >> 3;                 // log2(SPLIT)
  int i0 = bi * ROWT;
  int jb = s * JSP;

  int r16 = lane & 15;              // MFMA m (row) / B n (feature-in-group)
  int kg  = lane >> 4;              // k-group 0..3
  int irow = i0 + wv*16 + r16;

  float sti = st[irow];

  const int* ap            = adj + (size_t)irow*NO + jb + kg*8;
  const float* sop         = so + jb + kg*8;
  const unsigned short* hp = hob + (size_t)r16*NO + jb + kg*8;

  float4v acc0 = (float4v)0.f, acc1 = (float4v)0.f;
  float4v acc2 = (float4v)0.f, acc3 = (float4v)0.f;
  float dsum = 0.f;

#pragma unroll 1
  for (int tt = 0; tt < JSP/32; ++tt) {
    int off = tt*32;
    int4   a0 = *(const int4*)(ap + off);
    int4   a1 = *(const int4*)(ap + off + 4);
    float4 s0 = *(const float4*)(sop + off);
    float4 s1 = *(const float4*)(sop + off + 4);
    short8 b0 = *(const short8*)(hp + off);
    short8 b1 = *(const short8*)(hp + (size_t)16*NO + off);
    short8 b2 = *(const short8*)(hp + (size_t)32*NO + off);
    short8 b3 = *(const short8*)(hp + (size_t)48*NO + off);

    float x0 = sti + s0.x; x0 = fmaxf(x0, 0.2f*x0);
    float x1 = sti + s0.y; x1 = fmaxf(x1, 0.2f*x1);
    float x2 = sti + s0.z; x2 = fmaxf(x2, 0.2f*x2);
    float x3 = sti + s0.w; x3 = fmaxf(x3, 0.2f*x3);
    float x4 = sti + s1.x; x4 = fmaxf(x4, 0.2f*x4);
    float x5 = sti + s1.y; x5 = fmaxf(x5, 0.2f*x5);
    float x6 = sti + s1.z; x6 = fmaxf(x6, 0.2f*x6);
    float x7 = sti + s1.w; x7 = fmaxf(x7, 0.2f*x7);
    float w0 = (a0.x > 0) ? __expf(x0) : 0.f;
    float w1 = (a0.y > 0) ? __expf(x1) : 0.f;
    float w2 = (a0.z > 0) ? __expf(x2) : 0.f;
    float w3 = (a0.w > 0) ? __expf(x3) : 0.f;
    float w4 = (a1.x > 0) ? __expf(x4) : 0.f;
    float w5 = (a1.y > 0) ? __expf(x5) : 0.f;
    float w6 = (a1.z > 0) ? __expf(x6) : 0.f;
    float w7 = (a1.w > 0) ? __expf(x7) : 0.f;

    int p01 = pk2(w0, w1);
    int p23 = pk2(w2, w3);
    int p45 = pk2(w4, w5);
    int p67 = pk2(w6, w7);
    // den from the ROUNDED weights (num/den consistency)
    dsum += bflo(p01) + bfhi(p01) + bflo(p23) + bfhi(p23)
          + bflo(p45) + bfhi(p45) + bflo(p67) + bfhi(p67);

    int4 ai = {p01, p23, p45, p67};
    short8 afrag = *(short8*)&ai;

    acc0 = __builtin_amdgcn_mfma_f32_16x16x32_bf16(afrag, b0, acc0, 0, 0, 0);
    acc1 = __builtin_amdgcn_mfma_f32_16x16x32_bf16(afrag, b1, acc1, 0, 0, 0);
    acc2 = __builtin_amdgcn_mfma_f32_16x16x32_bf16(afrag, b2, acc2, 0, 0, 0);
    acc3 = __builtin_amdgcn_mfma_f32_16x16x32_bf16(afrag, b3, acc3, 0, 0, 0);
  }

  // den: sum the 4 k-group partials per row
  dsum += __shfl_xor(dsum, 16, 64);
  dsum += __shfl_xor(dsum, 32, 64);
  if (lane < 16) gden[(size_t)s*NT + i0 + wv*16 + lane] = dsum;

  // num partials: C/D layout col=lane&15, row=(lane>>4)*4+reg
  float4v accs[4] = {acc0, acc1, acc2, acc3};
#pragma unroll
  for (int g = 0; g < 4; ++g)
#pragma unroll
    for (int r = 0; r < 4; ++r) {
      int i = i0 + wv*16 + kg*4 + r;
      int f = g*16 + r16;
      gnum[((size_t)s*NT + i)*FOUT + f] = accs[g][r];
    }
}

// K6: combine splits, normalize, ELU
__global__ void k_comb(const float* __restrict__ ws, float* __restrict__ out) {
  int idx = blockIdx.x * 256 + threadIdx.x;   // 0..524287
  int i = idx >> 6;
  float num = 0.f, den = 0.f;
#pragma unroll
  for (int s = 0; s < SPLIT; ++s) {
    num += ws[OFF_NUM + ((size_t)s*NT + i)*FOUT + (idx & 63)];
    den += ws[OFF_DEN + (size_t)s*NT + i];
  }
  float r = num / den;
  out[idx] = (r > 0.f) ? r : (__expf(r) - 1.f);
}

extern "C" void kernel_launch(void* const* d_in, const int* in_sizes, int n_in,
                              void* d_out, int out_size, void* d_ws, size_t ws_size,
                              hipStream_t stream) {
  const float* tin = (const float*)d_in[0];
  const float* oin = (const float*)d_in[1];
  const float* Wt  = (const float*)d_in[2];
  const float* Wo  = (const float*)d_in[3];
  const float* a   = (const float*)d_in[4];
  const int*   adj = (const int*)d_in[5];
  float* out = (float*)d_out;
  float* ws  = (float*)d_ws;

  hipLaunchKernelGGL(k_wvec, dim3(1),              dim3(256), 0, stream, Wt, Wo, a, ws);
  hipLaunchKernelGGL(k_st,   dim3(NT/4),           dim3(256), 0, stream, tin, ws);
  hipLaunchKernelGGL(k_ho,   dim3(NO/32),          dim3(256), 0, stream, oin, Wo, a, ws);
  hipLaunchKernelGGL(k_attn, dim3(NT/ROWT*SPLIT),  dim3(256), 0, stream, adj, ws);
  hipLaunchKernelGGL(k_comb, dim3(NT*FOUT/256),    dim3(256), 0, stream, ws, out);
}

// Round 5
// 460.602 us; speedup vs baseline: 1.0409x; 1.0058x over previous
//
#include <hip/hip_runtime.h>
#include <math.h>

#define NT 8192
#define NO 8192
#define FIN 256
#define FOUT 64
#define SPLIT 8
#define JSP (NO/SPLIT)  // 1024 j per split
#define ROWT 64         // rows per attention block (4 waves x 16 rows)
#define NW32 (NO/32)    // mask dwords per row = 256

// workspace layout (float offsets)
#define OFF_ST  ((size_t)0)                           // 8192
#define OFF_SO  (OFF_ST + (size_t)NT)                 // 8192
#define OFF_WT  (OFF_SO + (size_t)NO)                 // 256
#define OFF_WO  (OFF_WT + (size_t)FIN)                // 256
#define OFF_NUM (OFF_WO + (size_t)FIN)                // SPLIT*8192*64
#define OFF_DEN (OFF_NUM + (size_t)SPLIT*NT*FOUT)     // SPLIT*8192
#define OFF_HOB (OFF_DEN + (size_t)SPLIT*NT)          // NO*FOUT bf16 (B-frag order)
#define OFF_ETA (OFF_HOB + (size_t)NO*FOUT/2)         // NO*2 floats (eso, eso2)
#define OFF_MSK (OFF_ETA + (size_t)NO*2)              // NT*NO/32 u32 bitmask
// total ~= 6.7M floats ~= 27 MB of d_ws

typedef __attribute__((ext_vector_type(8))) short short8;
typedef __attribute__((ext_vector_type(4))) float float4v;

static __device__ __forceinline__ unsigned short f2bf(float x) {
  unsigned int u = __float_as_uint(x);
  unsigned int r = (u + 0x7fffu + ((u >> 16) & 1u)) >> 16;   // RNE
  return (unsigned short)r;
}
static __device__ __forceinline__ int pk2(float a, float b) {
  return (int)((unsigned int)f2bf(a) | ((unsigned int)f2bf(b) << 16));
}
static __device__ __forceinline__ float bflo(int p) {
  return __uint_as_float(((unsigned int)p) << 16);
}
static __device__ __forceinline__ float bfhi(int p) {
  return __uint_as_float(((unsigned int)p) & 0xffff0000u);
}

// K0: bit-pack adjacency. 268 MB -> 8.4 MB, fully coalesced stream.
// Each wave-iter: lane l reads int4 (elements chunk*256 + l*4 .. +4, 1KB/instr
// coalesced), builds a nibble (linear bit order), gathers nibbles of 8 lanes
// into one dword via shfl-or, lanes l&7==0 store dwords. Bit b of word w =
// adjacency element w*32+b (linear).
__global__ void k_mask(const int* __restrict__ adj, float* __restrict__ ws) {
  unsigned int* mw = (unsigned int*)(ws + OFF_MSK);
  int wv = threadIdx.x >> 6, lane = threadIdx.x & 63;
  int gw = blockIdx.x * 4 + wv;          // 8192 waves
  const int NCH = NT*NO/256;             // 262144 chunks of 256 elements
#pragma unroll 2
  for (int c = gw; c < NCH; c += 8192) {
    int4 a = *(const int4*)(adj + (size_t)c*256 + lane*4);
    unsigned int nib = (a.x > 0 ? 1u : 0u) | (a.y > 0 ? 2u : 0u)
                     | (a.z > 0 ? 4u : 0u) | (a.w > 0 ? 8u : 0u);
    unsigned int val = nib << ((lane & 7) * 4);
    val |= __shfl_xor((int)val, 1, 64);
    val |= __shfl_xor((int)val, 2, 64);
    val |= __shfl_xor((int)val, 4, 64);
    if ((lane & 7) == 0) mw[(size_t)c*8 + (lane >> 3)] = val;
  }
}

// K1: fold wt = W_t @ a_t, wo = W_o @ a_o  (256-vectors)
__global__ void k_wvec(const float* __restrict__ Wt, const float* __restrict__ Wo,
                       const float* __restrict__ a, float* __restrict__ ws) {
  int k = threadIdx.x;  // 0..255
  float s1 = 0.f, s2 = 0.f;
#pragma unroll
  for (int fq = 0; fq < FOUT/4; ++fq) {
    float4 wt4 = *(const float4*)(Wt + (size_t)k*FOUT + fq*4);
    float4 wo4 = *(const float4*)(Wo + (size_t)k*FOUT + fq*4);
    float4 at4 = *(const float4*)(a + fq*4);
    float4 ao4 = *(const float4*)(a + FOUT + fq*4);
    s1 += wt4.x*at4.x + wt4.y*at4.y + wt4.z*at4.z + wt4.w*at4.w;
    s2 += wo4.x*ao4.x + wo4.y*ao4.y + wo4.z*ao4.z + wo4.w*ao4.w;
  }
  ws[OFF_WT + k] = s1;
  ws[OFF_WO + k] = s2;
}

// K2: s_t = t_input @ wt   (wave per row)
__global__ void k_st(const float* __restrict__ tin, float* __restrict__ ws) {
  int lane = threadIdx.x & 63;
  int wv   = threadIdx.x >> 6;
  int row  = blockIdx.x * 4 + wv;
  float4 v = ((const float4*)(tin + (size_t)row*FIN))[lane];
  float4 w = ((const float4*)(ws + OFF_WT))[lane];
  float p = v.x*w.x + v.y*w.y + v.z*w.z + v.w*w.w;
#pragma unroll
  for (int m = 32; m >= 1; m >>= 1) p += __shfl_xor(p, m, 64);
  if (lane == 0) ws[OFF_ST + row] = p;
}

// K3: h_o = o_input @ W_o (fp32). Outputs: hobp bf16 in EXACT B-fragment
// order (tile jt, fg, lane, e) so k_attn's B loads are coalesced 16B/lane;
// and s_o (fp32). 4 rows per wave, 512 blocks (2/CU).
__global__ void k_ho(const float* __restrict__ oin, const float* __restrict__ Wo,
                     const float* __restrict__ a, float* __restrict__ ws) {
  unsigned short* hobp = (unsigned short*)(ws + OFF_HOB);
  int lane = threadIdx.x & 63;
  int wv = __builtin_amdgcn_readfirstlane(threadIdx.x >> 6);
  int r0 = blockIdx.x * 16 + wv * 4;
  const float* ob = oin + (size_t)r0 * FIN;
  float acc[4];
#pragma unroll
  for (int r = 0; r < 4; ++r) acc[r] = 0.f;
#pragma unroll 2
  for (int k = 0; k < FIN; k += 4) {
    float w0 = Wo[(size_t)(k+0)*FOUT + lane];
    float w1 = Wo[(size_t)(k+1)*FOUT + lane];
    float w2 = Wo[(size_t)(k+2)*FOUT + lane];
    float w3 = Wo[(size_t)(k+3)*FOUT + lane];
#pragma unroll
    for (int r = 0; r < 4; ++r) {
      float4 ov = *(const float4*)(ob + (size_t)r*FIN + k);
      acc[r] = fmaf(ov.x, w0, acc[r]);
      acc[r] = fmaf(ov.y, w1, acc[r]);
      acc[r] = fmaf(ov.z, w2, acc[r]);
      acc[r] = fmaf(ov.w, w3, acc[r]);
    }
  }
  float ao = a[FOUT + lane];
  int fg = lane >> 4, n16 = lane & 15;
#pragma unroll
  for (int r = 0; r < 4; ++r) {
    int j = r0 + r;
    int jt = j >> 5, jl = j & 31;
    int ldst = (jl >> 3) * 16 + n16;      // consumer lane
    int e = jl & 7;
    hobp[(((size_t)jt*4 + fg)*64 + ldst)*8 + e] = f2bf(acc[r]);
    float p = acc[r] * ao;
#pragma unroll
    for (int m = 32; m >= 1; m >>= 1) p += __shfl_xor(p, m, 64);
    if (lane == 0) ws[OFF_SO + j] = p;
  }
}

// K4: exp tables: etab[2j] = exp(s_o[j]), etab[2j+1] = exp(0.2*s_o[j]).
__global__ void k_etab(float* __restrict__ ws) {
  int j = blockIdx.x * 256 + threadIdx.x;
  float s = ws[OFF_SO + j];
  ws[OFF_ETA + 2*j + 0] = __expf(s);
  ws[OFF_ETA + 2*j + 1] = __expf(0.2f * s);
}

// K5: fused masked-softmax attention. Zero LDS/barriers; all inner-loop data
// L1/L2-resident (mask bits 8.4 MB, hobp 1 MB, etab 64 KB). No exp in loop:
// w = exp(leaky(st+so)) = (so >= -st) ? exp(st)exp(so) : exp(.2st)exp(.2so),
// branch via monotone compare eso >= exp(-st). den from bf16-rounded w.
// A-frag in registers: lane l = row l&15, k-cols (l>>4)*8..+8 (source map
// row l>>2 / chunk l&3 then 4x ds_bpermute after packing).
__launch_bounds__(256, 4)
__global__ void k_attn(float* __restrict__ ws) {
  const float* st = ws + OFF_ST;
  const float* etab = ws + OFF_ETA;
  const unsigned int* maskw = (const unsigned int*)(ws + OFF_MSK);
  const unsigned short* hobp = (const unsigned short*)(ws + OFF_HOB);
  float* gnum = ws + OFF_NUM;
  float* gden = ws + OFF_DEN;

  int t = threadIdx.x;
  int wv = t >> 6, lane = t & 63;
  int bx = blockIdx.x;
  int s  = bx & (SPLIT - 1);
  int bi = bx >> 3;                 // log2(SPLIT)
  int i0 = bi * ROWT;
  int jb = s * JSP;

  // source-lane mapping (coalesced loads): row rsrc = lane>>2, chunk csrc = lane&3
  int rsrc = lane >> 2, csrc = lane & 3;
  int irow_s = i0 + wv*16 + rsrc;
  float sti  = st[irow_s];
  float esti  = __expf(sti);
  float esti2 = __expf(0.2f * sti);
  float ethr  = __expf(-sti);

  const unsigned int* mrow = maskw + (size_t)irow_s * NW32 + (jb >> 5);
  const float* ep = etab + (size_t)(jb + csrc*8) * 2;
  const unsigned short* hpb = hobp + (size_t)(jb >> 5) * 2048 + lane*8;

  // target-lane A-frag mapping + bpermute source index
  int r16 = lane & 15, kg = lane >> 4;
  int sidx4 = ((r16 * 4 + kg) << 2);

  float4v acc0 = (float4v)0.f, acc1 = (float4v)0.f;
  float4v acc2 = (float4v)0.f, acc3 = (float4v)0.f;
  float dsum = 0.f;

#pragma unroll 1
  for (int tt = 0; tt < JSP/32; ++tt) {
    unsigned int mwv = mrow[tt];
    const float* e_ = ep + tt*64;
    float4 e0 = *(const float4*)(e_);        // (eso,eso2) cols +0,+1
    float4 e1 = *(const float4*)(e_ + 4);    // +2,+3
    float4 e2 = *(const float4*)(e_ + 8);    // +4,+5
    float4 e3 = *(const float4*)(e_ + 12);   // +6,+7
    const unsigned short* hb = hpb + (size_t)tt*2048;
    short8 b0 = *(const short8*)(hb);
    short8 b1 = *(const short8*)(hb + 512);
    short8 b2 = *(const short8*)(hb + 1024);
    short8 b3 = *(const short8*)(hb + 1536);

    unsigned int msh = mwv >> (csrc * 8);
    float w0 = ((e0.x >= ethr) ? esti*e0.x : esti2*e0.y); w0 = (msh & 1u)   ? w0 : 0.f;
    float w1 = ((e0.z >= ethr) ? esti*e0.z : esti2*e0.w); w1 = (msh & 2u)   ? w1 : 0.f;
    float w2 = ((e1.x >= ethr) ? esti*e1.x : esti2*e1.y); w2 = (msh & 4u)   ? w2 : 0.f;
    float w3 = ((e1.z >= ethr) ? esti*e1.z : esti2*e1.w); w3 = (msh & 8u)   ? w3 : 0.f;
    float w4 = ((e2.x >= ethr) ? esti*e2.x : esti2*e2.y); w4 = (msh & 16u)  ? w4 : 0.f;
    float w5 = ((e2.z >= ethr) ? esti*e2.z : esti2*e2.w); w5 = (msh & 32u)  ? w5 : 0.f;
    float w6 = ((e3.x >= ethr) ? esti*e3.x : esti2*e3.y); w6 = (msh & 64u)  ? w6 : 0.f;
    float w7 = ((e3.z >= ethr) ? esti*e3.z : esti2*e3.w); w7 = (msh & 128u) ? w7 : 0.f;

    int p0 = pk2(w0, w1);
    int p1 = pk2(w2, w3);
    int p2 = pk2(w4, w5);
    int p3 = pk2(w6, w7);
    dsum += bflo(p0) + bfhi(p0) + bflo(p1) + bfhi(p1)
          + bflo(p2) + bfhi(p2) + bflo(p3) + bfhi(p3);

    int4 ai;
    ai.x = __builtin_amdgcn_ds_bpermute(sidx4, p0);
    ai.y = __builtin_amdgcn_ds_bpermute(sidx4, p1);
    ai.z = __builtin_amdgcn_ds_bpermute(sidx4, p2);
    ai.w = __builtin_amdgcn_ds_bpermute(sidx4, p3);
    short8 afrag = *(short8*)&ai;

    acc0 = __builtin_amdgcn_mfma_f32_16x16x32_bf16(afrag, b0, acc0, 0, 0, 0);
    acc1 = __builtin_amdgcn_mfma_f32_16x16x32_bf16(afrag, b1, acc1, 0, 0, 0);
    acc2 = __builtin_amdgcn_mfma_f32_16x16x32_bf16(afrag, b2, acc2, 0, 0, 0);
    acc3 = __builtin_amdgcn_mfma_f32_16x16x32_bf16(afrag, b3, acc3, 0, 0, 0);
  }

  // den: dsum is per (row rsrc, chunk csrc) — reduce over the 4 chunks
  dsum += __shfl_xor(dsum, 1, 64);
  dsum += __shfl_xor(dsum, 2, 64);
  if (csrc == 0) gden[(size_t)s*NT + i0 + wv*16 + rsrc] = dsum;

  // num partials: C/D layout col=lane&15, row=(lane>>4)*4+reg
  size_t obase = ((size_t)s*NT + i0 + wv*16 + kg*4) * FOUT + r16;
#pragma unroll
  for (int r = 0; r < 4; ++r) {
    gnum[obase + (size_t)r*FOUT +  0] = acc0[r];
    gnum[obase + (size_t)r*FOUT + 16] = acc1[r];
    gnum[obase + (size_t)r*FOUT + 32] = acc2[r];
    gnum[obase + (size_t)r*FOUT + 48] = acc3[r];
  }
}

// K6: combine splits, normalize, ELU
__global__ void k_comb(const float* __restrict__ ws, float* __restrict__ out) {
  int idx = blockIdx.x * 256 + threadIdx.x;   // 0..524287
  int i = idx >> 6;
  float num = 0.f, den = 0.f;
#pragma unroll
  for (int s = 0; s < SPLIT; ++s) {
    num += ws[OFF_NUM + ((size_t)s*NT + i)*FOUT + (idx & 63)];
    den += ws[OFF_DEN + (size_t)s*NT + i];
  }
  float r = num / den;
  out[idx] = (r > 0.f) ? r : (__expf(r) - 1.f);
}

extern "C" void kernel_launch(void* const* d_in, const int* in_sizes, int n_in,
                              void* d_out, int out_size, void* d_ws, size_t ws_size,
                              hipStream_t stream) {
  const float* tin = (const float*)d_in[0];
  const float* oin = (const float*)d_in[1];
  const float* Wt  = (const float*)d_in[2];
  const float* Wo  = (const float*)d_in[3];
  const float* a   = (const float*)d_in[4];
  const int*   adj = (const int*)d_in[5];
  float* out = (float*)d_out;
  float* ws  = (float*)d_ws;

  hipLaunchKernelGGL(k_mask, dim3(2048),           dim3(256), 0, stream, adj, ws);
  hipLaunchKernelGGL(k_wvec, dim3(1),              dim3(256), 0, stream, Wt, Wo, a, ws);
  hipLaunchKernelGGL(k_st,   dim3(NT/4),           dim3(256), 0, stream, tin, ws);
  hipLaunchKernelGGL(k_ho,   dim3(NO/16),          dim3(256), 0, stream, oin, Wo, a, ws);
  hipLaunchKernelGGL(k_etab, dim3(NO/256),         dim3(256), 0, stream, ws);
  hipLaunchKernelGGL(k_attn, dim3(NT/ROWT*SPLIT),  dim3(256), 0, stream, ws);
  hipLaunchKernelGGL(k_comb, dim3(NT*FOUT/256),    dim3(256), 0, stream, ws, out);
}